// Round 1
// baseline (710.025 us; speedup 1.0000x reference)
//
#include <hip/hip_runtime.h>

// ---------------------------------------------------------------------------
// MultiheadAttention2: qp = q@Wq.T ; kp = qp@Wk.T (quirk) ; vp = v@Wv.T
// att = softmax(causal(qh kh^T * sqrt(D))) ; y = att vh ; out = y@Wp.T + bp
// Score path (qp, kp, QK^T) uses split-precision bf16 (hi/lo, 3 MFMAs) so the
// sharp softmax (logit std ~17) sees ~fp32-accurate logits. Value path plain bf16.
// Workspace: 6 arrays of M*E bf16 = 96 MiB.
// ---------------------------------------------------------------------------

typedef unsigned short u16;
typedef unsigned int   u32;
typedef __attribute__((ext_vector_type(8))) __bf16 bf16x8;
typedef __attribute__((ext_vector_type(8))) u16    u16x8;
typedef __attribute__((ext_vector_type(4))) u16    u16x4;
typedef __attribute__((ext_vector_type(4))) float  f32x4;

#define DEV static __device__ __forceinline__

DEV u16 f2bf(float x){ union{float f;u32 u;}v; v.f=x; u32 r=v.u+0x7fffu+((v.u>>16)&1u); return (u16)(r>>16); }
DEV float bf2f(u16 b){ union{u32 u;float f;}v; v.u=((u32)b)<<16; return v.f; }
DEV f32x4 zero4(){ f32x4 z={0.f,0.f,0.f,0.f}; return z; }
DEV f32x4 mfma16(bf16x8 a, bf16x8 b, f32x4 c){ return __builtin_amdgcn_mfma_f32_16x16x32_bf16(a,b,c,0,0,0); }

constexpr int B_=4, T_=2048, E_=1024, H_=16;
constexpr int M_=B_*T_;            // 8192 rows

// ---------------------------------------------------------------------------
// GEMM: C[M,N] = A[M,K] @ W[N,K]^T   (torch Linear), M=8192, N=K=1024
// MODE 0: A fp32 (split in staging),  W split -> out hi/lo bf16   (qp)
// MODE 1: A bf16 hi/lo,               W split -> out hi/lo bf16   (kp)
// MODE 2: A fp32 plain,               W plain -> out bf16         (vp)
// MODE 3: A bf16 plain,               W plain -> out fp32 + bias  (final)
// 128x128 block, BK=32, 4 waves (2x2 of 64x64), 16x16x32 bf16 MFMA.
// ---------------------------------------------------------------------------
template<int MODE>
__global__ __launch_bounds__(256)
void gemm_nt(const float* __restrict__ Af, const u16* __restrict__ Ahi_g, const u16* __restrict__ Alo_g,
             const float* __restrict__ W,  const float* __restrict__ bias,
             u16* __restrict__ Ohi, u16* __restrict__ Olo, float* __restrict__ Of)
{
  constexpr bool SPLIT = (MODE==0)||(MODE==1);
  constexpr int PITCH=40;                 // 32 + 8 pad: conflict-free ds_read_b128
  __shared__ u16 sAh[128*PITCH];
  __shared__ u16 sBh[128*PITCH];
  __shared__ u16 sAl[SPLIT?128*PITCH:8];
  __shared__ u16 sBl[SPLIT?128*PITCH:8];

  const int tid=threadIdx.x, wave=tid>>6, lane=tid&63;
  const int quad=lane>>4, l16=lane&15;
  const int wm=(wave>>1)*64, wn=(wave&1)*64;
  const int n0=blockIdx.x*128, m0=blockIdx.y*128;
  const int K=E_;

  f32x4 acc[4][4];
#pragma unroll
  for(int i=0;i<4;i++)
#pragma unroll
    for(int j=0;j<4;j++) acc[i][j]=zero4();

  for(int k0=0;k0<K;k0+=32){
    // ---- stage A tile (128x32) ----
    if (MODE==0 || MODE==2){
#pragma unroll
      for(int it=0;it<4;it++){
        int c=it*256+tid, row=c>>3, col=(c&7)*4;
        f32x4 v=*reinterpret_cast<const f32x4*>(Af + (size_t)(m0+row)*K + k0+col);
        u16x4 h,l;
#pragma unroll
        for(int j=0;j<4;j++){ u16 hh=f2bf(v[j]); h[j]=hh; l[j]=f2bf(v[j]-bf2f(hh)); }
        *reinterpret_cast<u16x4*>(&sAh[row*PITCH+col])=h;
        if (MODE==0) *reinterpret_cast<u16x4*>(&sAl[row*PITCH+col])=l;
      }
    } else {
#pragma unroll
      for(int it=0;it<2;it++){
        int c=it*256+tid, row=c>>2, col=(c&3)*8;
        size_t off=(size_t)(m0+row)*K + k0+col;
        *reinterpret_cast<u16x8*>(&sAh[row*PITCH+col]) = *reinterpret_cast<const u16x8*>(Ahi_g+off);
        if (MODE==1)
          *reinterpret_cast<u16x8*>(&sAl[row*PITCH+col]) = *reinterpret_cast<const u16x8*>(Alo_g+off);
      }
    }
    // ---- stage W tile (128x32, always fp32 source) ----
#pragma unroll
    for(int it=0;it<4;it++){
      int c=it*256+tid, row=c>>3, col=(c&7)*4;
      f32x4 v=*reinterpret_cast<const f32x4*>(W + (size_t)(n0+row)*K + k0+col);
      u16x4 h,l;
#pragma unroll
      for(int j=0;j<4;j++){ u16 hh=f2bf(v[j]); h[j]=hh; l[j]=f2bf(v[j]-bf2f(hh)); }
      *reinterpret_cast<u16x4*>(&sBh[row*PITCH+col])=h;
      if (SPLIT) *reinterpret_cast<u16x4*>(&sBl[row*PITCH+col])=l;
    }
    __syncthreads();

    bf16x8 ah[4],bh[4],al[4],bl[4];
#pragma unroll
    for(int i=0;i<4;i++){
      ah[i]=*reinterpret_cast<const bf16x8*>(&sAh[(wm+i*16+l16)*PITCH+quad*8]);
      bh[i]=*reinterpret_cast<const bf16x8*>(&sBh[(wn+i*16+l16)*PITCH+quad*8]);
      if (SPLIT){
        al[i]=*reinterpret_cast<const bf16x8*>(&sAl[(wm+i*16+l16)*PITCH+quad*8]);
        bl[i]=*reinterpret_cast<const bf16x8*>(&sBl[(wn+i*16+l16)*PITCH+quad*8]);
      }
    }
#pragma unroll
    for(int i=0;i<4;i++)
#pragma unroll
      for(int j=0;j<4;j++){
        acc[i][j]=mfma16(ah[i],bh[j],acc[i][j]);
        if (SPLIT){
          acc[i][j]=mfma16(ah[i],bl[j],acc[i][j]);   // hi * lo
          acc[i][j]=mfma16(al[i],bh[j],acc[i][j]);   // lo * hi
        }
      }
    __syncthreads();
  }

  // ---- epilogue ----  D layout: row = quad*4+r, col = lane&15
#pragma unroll
  for(int i=0;i<4;i++)
#pragma unroll
    for(int j=0;j<4;j++){
      int col = n0 + wn + j*16 + l16;
#pragma unroll
      for(int r=0;r<4;r++){
        int row = m0 + wm + i*16 + quad*4 + r;
        size_t idx=(size_t)row*E_ + col;
        float v = acc[i][j][r];
        if (MODE==3)      Of[idx]  = v + bias[col];
        else if (MODE==2) Ohi[idx] = f2bf(v);
        else { u16 hh=f2bf(v); Ohi[idx]=hh; Olo[idx]=f2bf(v - bf2f(hh)); }
      }
    }
}

// ---------------------------------------------------------------------------
// Flash attention. Block = 4 waves x 32 q-rows = 128 q rows per block.
// Grid (T/128, B*H). K-tiles of 64, shared K(hi/lo)/V staging; V transposed in
// LDS so its MFMA B-frag reads are contiguous. Scores via 3-term split MFMA.
// P goes C-layout -> LDS -> A-layout for P·V (per guide §3 / m120).
// ---------------------------------------------------------------------------
__global__ __launch_bounds__(256)
void attn(const u16* __restrict__ qph, const u16* __restrict__ qpl,
          const u16* __restrict__ kph, const u16* __restrict__ kpl,
          const u16* __restrict__ vph, u16* __restrict__ yout)
{
  constexpr int PIT=72;                   // 64 + 8 pad
  __shared__ u16 sKh[64*PIT];
  __shared__ u16 sKl[64*PIT];
  __shared__ u16 sV [64*PIT];             // transposed: [d][s]
  __shared__ u16 sP [4][32*PIT];          // per-wave P scratch

  const int tid=threadIdx.x, wave=tid>>6, lane=tid&63;
  const int quad=lane>>4, l16=lane&15;
  const int qt=blockIdx.x, bh=blockIdx.y;
  const int b=bh>>4, h=bh&15;
  const int qr0=qt*128 + wave*32;         // this wave's first q row

  // Q fragments (hi/lo) in registers: A[m=lane&15][k=quad*8+j], k over D=64
  bf16x8 qfh[2][2], qfl[2][2];
#pragma unroll
  for(int mt=0;mt<2;mt++)
#pragma unroll
    for(int ks=0;ks<2;ks++){
      size_t off=(size_t)(b*T_ + qr0 + mt*16 + l16)*E_ + h*64 + ks*32 + quad*8;
      qfh[mt][ks]=*reinterpret_cast<const bf16x8*>(qph+off);
      qfl[mt][ks]=*reinterpret_cast<const bf16x8*>(qpl+off);
    }

  float mst[2][4], lst[2][4];
  f32x4 oacc[2][4];
#pragma unroll
  for(int mt=0;mt<2;mt++){
#pragma unroll
    for(int r=0;r<4;r++){ mst[mt][r]=-1e30f; lst[mt][r]=0.f; }
#pragma unroll
    for(int dt=0;dt<4;dt++) oacc[mt][dt]=zero4();
  }

  const int nkt=2*(qt+1);
  for(int kt=0;kt<nkt;kt++){
    const int s0=kt*64;
    __syncthreads();                      // previous tile's LDS reads done
    // stage K hi/lo (64 s x 64 d), row-major
#pragma unroll
    for(int it=0;it<2;it++){
      int c=it*256+tid, s=c>>3, dc=(c&7)*8;
      size_t off=(size_t)(b*T_+s0+s)*E_ + h*64 + dc;
      *reinterpret_cast<u16x8*>(&sKh[s*PIT+dc]) = *reinterpret_cast<const u16x8*>(kph+off);
      *reinterpret_cast<u16x8*>(&sKl[s*PIT+dc]) = *reinterpret_cast<const u16x8*>(kpl+off);
    }
    // stage V transposed: sV[d][s]
#pragma unroll
    for(int it=0;it<2;it++){
      int c=it*256+tid, s=c&63, dc=(c>>6)*8;
      size_t off=(size_t)(b*T_+s0+s)*E_ + h*64 + dc;
      u16x8 vv=*reinterpret_cast<const u16x8*>(vph+off);
#pragma unroll
      for(int j=0;j<8;j++) sV[(dc+j)*PIT + s] = vv[j];
    }
    __syncthreads();

    if (s0 <= qr0+31){                    // tile not fully masked for this wave
      // ---- S = Q K^T (split precision) ----
      f32x4 sacc[2][4];
#pragma unroll
      for(int mt=0;mt<2;mt++)
#pragma unroll
        for(int nt=0;nt<4;nt++) sacc[mt][nt]=zero4();
#pragma unroll
      for(int nt=0;nt<4;nt++)
#pragma unroll
        for(int ks=0;ks<2;ks++){
          bf16x8 kh=*reinterpret_cast<const bf16x8*>(&sKh[(nt*16+l16)*PIT+ks*32+quad*8]);
          bf16x8 kl=*reinterpret_cast<const bf16x8*>(&sKl[(nt*16+l16)*PIT+ks*32+quad*8]);
#pragma unroll
          for(int mt=0;mt<2;mt++){
            sacc[mt][nt]=mfma16(qfh[mt][ks],kh,sacc[mt][nt]);
            sacc[mt][nt]=mfma16(qfh[mt][ks],kl,sacc[mt][nt]);
            sacc[mt][nt]=mfma16(qfl[mt][ks],kh,sacc[mt][nt]);
          }
        }
      const bool needmask = (s0+63 > qr0);
      // ---- online softmax (quirk: multiply by sqrt(D)=8) ----
#pragma unroll
      for(int mt=0;mt<2;mt++)
#pragma unroll
        for(int r=0;r<4;r++){
          const int qrow = qr0 + mt*16 + quad*4 + r;
          float mx=-1e30f;
#pragma unroll
          for(int nt=0;nt<4;nt++){
            float vsc = sacc[mt][nt][r]*8.0f;
            if (needmask && (s0+nt*16+l16 > qrow)) vsc=-1e30f;
            sacc[mt][nt][r]=vsc;
            mx=fmaxf(mx,vsc);
          }
#pragma unroll
          for(int off=1;off<16;off<<=1) mx=fmaxf(mx,__shfl_xor(mx,off,64));
          float nm=fmaxf(mst[mt][r],mx);
          float alpha=__expf(mst[mt][r]-nm);
          mst[mt][r]=nm;
          float rsum=0.f;
#pragma unroll
          for(int nt=0;nt<4;nt++){
            float p=__expf(sacc[mt][nt][r]-nm);
            sacc[mt][nt][r]=p;
            rsum+=p;
          }
#pragma unroll
          for(int off=1;off<16;off<<=1) rsum+=__shfl_xor(rsum,off,64);
          lst[mt][r]=lst[mt][r]*alpha+rsum;
#pragma unroll
          for(int dt=0;dt<4;dt++) oacc[mt][dt][r]*=alpha;
#pragma unroll
          for(int nt=0;nt<4;nt++)
            sP[wave][(mt*16+quad*4+r)*PIT + nt*16 + l16]=f2bf(sacc[mt][nt][r]);
        }
      asm volatile("s_waitcnt lgkmcnt(0)" ::: "memory");   // P writes visible to own wave's reads
      // ---- O += P V ----
      bf16x8 pf[2][2];
#pragma unroll
      for(int mt=0;mt<2;mt++)
#pragma unroll
        for(int ks=0;ks<2;ks++)
          pf[mt][ks]=*reinterpret_cast<const bf16x8*>(&sP[wave][(mt*16+l16)*PIT+ks*32+quad*8]);
#pragma unroll
      for(int dt=0;dt<4;dt++)
#pragma unroll
        for(int ks=0;ks<2;ks++){
          bf16x8 vf=*reinterpret_cast<const bf16x8*>(&sV[(dt*16+l16)*PIT+ks*32+quad*8]);
#pragma unroll
          for(int mt=0;mt<2;mt++)
            oacc[mt][dt]=mfma16(pf[mt][ks],vf,oacc[mt][dt]);
        }
    }
  }
  // ---- y = O / l, bf16, layout [B,T,E] ----
#pragma unroll
  for(int mt=0;mt<2;mt++)
#pragma unroll
    for(int dt=0;dt<4;dt++)
#pragma unroll
      for(int r=0;r<4;r++){
        int qrow=qr0+mt*16+quad*4+r;
        int d=dt*16+l16;
        float v=oacc[mt][dt][r]/lst[mt][r];
        yout[(size_t)(b*T_+qrow)*E_ + h*64 + d]=f2bf(v);
      }
}

// ---------------------------------------------------------------------------
extern "C" void kernel_launch(void* const* d_in, const int* in_sizes, int n_in,
                              void* d_out, int out_size, void* d_ws, size_t ws_size,
                              hipStream_t stream)
{
  const float* q =(const float*)d_in[0];
  // d_in[1] (k) is UNUSED: reference quirk computes kp from qp.
  const float* v =(const float*)d_in[2];
  const float* Wq=(const float*)d_in[3];
  const float* Wk=(const float*)d_in[4];
  const float* Wv=(const float*)d_in[5];
  const float* Wp=(const float*)d_in[6];
  const float* bp=(const float*)d_in[7];
  float* out=(float*)d_out;

  const size_t NE=(size_t)M_*E_;          // 8.39M elems; 6 bf16 arrays = 96 MiB ws
  u16* qph=(u16*)d_ws;
  u16* qpl=qph+NE;
  u16* kph=qpl+NE;
  u16* kpl=kph+NE;
  u16* vpb=kpl+NE;
  u16* ybf=vpb+NE;

  dim3 blk(256), g(E_/128, M_/128);
  gemm_nt<0><<<g, blk, 0, stream>>>(q, nullptr, nullptr, Wq, nullptr, qph, qpl, nullptr);
  gemm_nt<1><<<g, blk, 0, stream>>>(nullptr, qph, qpl,   Wk, nullptr, kph, kpl, nullptr);
  gemm_nt<2><<<g, blk, 0, stream>>>(v, nullptr, nullptr, Wv, nullptr, vpb, nullptr, nullptr);
  attn<<<dim3(T_/128, B_*H_), blk, 0, stream>>>(qph, qpl, kph, kpl, vpb, ybf);
  gemm_nt<3><<<g, blk, 0, stream>>>(nullptr, ybf, nullptr, Wp, bp, nullptr, nullptr, out);
}

// Round 2
// 484.661 us; speedup vs baseline: 1.4650x; 1.4650x over previous
//
#include <hip/hip_runtime.h>

// ---------------------------------------------------------------------------
// qp = q@Wq.T ; kp = qp@Wk.T (quirk) ; vp = v@Wv.T
// att = softmax(causal(q k^T * sqrt(D))) ; y = att v ; out = y@Wp.T + bp
// Score path in split bf16 (hi/lo, 3-term MFMA) -> ~fp32 logits (round-1
// validated: absmax 0.0078 vs 0.0403). Round-2: S^T orientation in attention
// (kills sP LDS round-trip; softmax reduces in-lane), global_load_lds staging
// everywhere, pre-converted operands, descending-work block order.
// ws: 6 x NE bf16 = 96 MiB (proven). Weight splits live in d_out scratch
// (10 MB, dead until final GEMM which reads fp32 Wp directly).
// ---------------------------------------------------------------------------

typedef unsigned short u16;
typedef unsigned int   u32;
typedef __attribute__((ext_vector_type(8))) __bf16 bf16x8;
typedef __attribute__((ext_vector_type(8))) u16    u16x8;
typedef __attribute__((ext_vector_type(4))) u16    u16x4;
typedef __attribute__((ext_vector_type(4))) float  f32x4;
typedef __attribute__((ext_vector_type(4))) int    i32x4;

#define DEV static __device__ __forceinline__

DEV u16 f2bf(float x){ union{float f;u32 u;}v; v.f=x; u32 r=v.u+0x7fffu+((v.u>>16)&1u); return (u16)(r>>16); }
DEV float bf2f(u16 b){ union{u32 u;float f;}v; v.u=((u32)b)<<16; return v.f; }
DEV f32x4 zero4(){ f32x4 z={0.f,0.f,0.f,0.f}; return z; }
DEV f32x4 mfma16(bf16x8 a, bf16x8 b, f32x4 c){ return __builtin_amdgcn_mfma_f32_16x16x32_bf16(a,b,c,0,0,0); }
// async global->LDS, 16B/lane, LDS dest = wave-uniform base + lane*16
DEV void gld16(const u16* g, u16* l){
  __builtin_amdgcn_global_load_lds((const __attribute__((address_space(1))) u32*)g,
                                   (__attribute__((address_space(3))) u32*)l, 16, 0, 0);
}

constexpr int B_=4, T_=2048, E_=1024;
constexpr int M_=B_*T_;                  // 8192

// ---------------------------------------------------------------------------
// Pre-convert kernels (run once per launch; all scratch rewritten every call)
// ---------------------------------------------------------------------------
__global__ __launch_bounds__(256) void cvt_w(const float* __restrict__ Wq, const float* __restrict__ Wk,
                                             const float* __restrict__ Wv,
                                             u16* wqh,u16* wql,u16* wkh,u16* wkl,u16* wvb)
{
  const int j=blockIdx.y;
  const float* s = (j==0)?Wq : (j==1)?Wk : Wv;
  size_t i = ((size_t)blockIdx.x*256 + threadIdx.x)*4;
  f32x4 v = *reinterpret_cast<const f32x4*>(s+i);
  u16x4 h,l;
#pragma unroll
  for(int t=0;t<4;t++){ u16 hh=f2bf(v[t]); h[t]=hh; l[t]=f2bf(v[t]-bf2f(hh)); }
  if(j==0){ *reinterpret_cast<u16x4*>(wqh+i)=h; *reinterpret_cast<u16x4*>(wql+i)=l; }
  else if(j==1){ *reinterpret_cast<u16x4*>(wkh+i)=h; *reinterpret_cast<u16x4*>(wkl+i)=l; }
  else { *reinterpret_cast<u16x4*>(wvb+i)=h; }
}

__global__ __launch_bounds__(256) void cvt_a(const float* __restrict__ q, const float* __restrict__ v,
                                             u16* qsh,u16* qsl,u16* vb)
{
  const int j=blockIdx.y;
  size_t i = ((size_t)blockIdx.x*256 + threadIdx.x)*4;
  const float* s = (j==0)?q:v;
  f32x4 x = *reinterpret_cast<const f32x4*>(s+i);
  u16x4 h,l;
#pragma unroll
  for(int t=0;t<4;t++){ u16 hh=f2bf(x[t]); h[t]=hh; l[t]=f2bf(x[t]-bf2f(hh)); }
  if(j==0){ *reinterpret_cast<u16x4*>(qsh+i)=h; *reinterpret_cast<u16x4*>(qsl+i)=l; }
  else { *reinterpret_cast<u16x4*>(vb+i)=h; }
}

// ---------------------------------------------------------------------------
// GEMM  C[M,N] = A[M,K] @ W[N,K]^T, M=8192, N=K=1024. 128x128 tile, BK=32,
// 4 waves (2x2 of 64x64). Staging via global_load_lds dwordx4 (m97 recipe).
// ASPLIT/WSPLIT: 3-term split MFMA. WF32: W staged from fp32 + in-loop cvt
// (final GEMM only). OMODE: 0 = split bf16 out, 1 = bf16 out, 2 = f32+bias.
// ---------------------------------------------------------------------------
template<int ASPLIT,int WSPLIT,int WF32,int OMODE>
__global__ __launch_bounds__(256)
void gemm(const u16* __restrict__ Ah, const u16* __restrict__ Al,
          const u16* __restrict__ Wh, const u16* __restrict__ Wl,
          const float* __restrict__ Wf, const float* __restrict__ bias,
          u16* __restrict__ Ohi, u16* __restrict__ Olo, float* __restrict__ Of)
{
  constexpr int WPIT = WF32 ? 40 : 32;
  __shared__ u16 sAh[128*32];
  __shared__ u16 sAl[ASPLIT?128*32:8];
  __shared__ u16 sBh[128*WPIT];
  __shared__ u16 sBl[WSPLIT?128*WPIT:8];

  const int tid=threadIdx.x, wave=tid>>6, lane=tid&63;
  const int quad=lane>>4, l16=lane&15;
  const int wm=(wave>>1)*64, wn=(wave&1)*64;
  const int n0=blockIdx.x*128, m0=blockIdx.y*128;

  f32x4 acc[4][4];
#pragma unroll
  for(int i=0;i<4;i++)
#pragma unroll
    for(int j=0;j<4;j++) acc[i][j]=zero4();

  for(int k0=0;k0<E_;k0+=32){
    // ---- A tiles: async 16B/lane ----
#pragma unroll
    for(int it=0;it<2;it++){
      const int chunk=it*256+tid;
      const size_t goff=(size_t)(m0+(chunk>>2))*E_ + k0 + (chunk&3)*8;
      u16* ldst=&sAh[(it*256+wave*64)*8];
      gld16(Ah+goff, ldst);
      if(ASPLIT) gld16(Al+goff, &sAl[(it*256+wave*64)*8]);
    }
    // ---- W tiles ----
    if(!WF32){
#pragma unroll
      for(int it=0;it<2;it++){
        const int chunk=it*256+tid;
        const size_t goff=(size_t)(n0+(chunk>>2))*E_ + k0 + (chunk&3)*8;
        gld16(Wh+goff, &sBh[(it*256+wave*64)*8]);
        if(WSPLIT) gld16(Wl+goff, &sBl[(it*256+wave*64)*8]);
      }
    } else {
#pragma unroll
      for(int it=0;it<4;it++){
        int c=it*256+tid, row=c>>3, col=(c&7)*4;
        f32x4 w=*reinterpret_cast<const f32x4*>(Wf + (size_t)(n0+row)*E_ + k0+col);
        u16x4 h;
#pragma unroll
        for(int t=0;t<4;t++) h[t]=f2bf(w[t]);
        *reinterpret_cast<u16x4*>(&sBh[row*WPIT+col])=h;
      }
    }
    __syncthreads();

    bf16x8 ah[4],bh[4],al[4],bl[4];
#pragma unroll
    for(int i=0;i<4;i++){
      ah[i]=*reinterpret_cast<const bf16x8*>(&sAh[(wm+i*16+l16)*32+quad*8]);
      bh[i]=*reinterpret_cast<const bf16x8*>(&sBh[(wn+i*16+l16)*WPIT+quad*8]);
      if(ASPLIT) al[i]=*reinterpret_cast<const bf16x8*>(&sAl[(wm+i*16+l16)*32+quad*8]);
      if(WSPLIT) bl[i]=*reinterpret_cast<const bf16x8*>(&sBl[(wn+i*16+l16)*WPIT+quad*8]);
    }
#pragma unroll
    for(int i=0;i<4;i++)
#pragma unroll
      for(int j=0;j<4;j++){
        acc[i][j]=mfma16(ah[i],bh[j],acc[i][j]);
        if(WSPLIT) acc[i][j]=mfma16(ah[i],bl[j],acc[i][j]);
        if(ASPLIT) acc[i][j]=mfma16(al[i],bh[j],acc[i][j]);
      }
    __syncthreads();
  }

  // epilogue: D row = quad*4+r, col = l16 (verified round 1)
#pragma unroll
  for(int i=0;i<4;i++)
#pragma unroll
    for(int j=0;j<4;j++){
      const int col=n0+wn+j*16+l16;
#pragma unroll
      for(int r=0;r<4;r++){
        const int row=m0+wm+i*16+quad*4+r;
        const size_t idx=(size_t)row*E_+col;
        float v=acc[i][j][r];
        if(OMODE==2)      Of[idx]=v+bias[col];
        else if(OMODE==1) Ohi[idx]=f2bf(v);
        else { u16 hh=f2bf(v); Ohi[idx]=hh; Olo[idx]=f2bf(v-bf2f(hh)); }
      }
    }
}

// ---------------------------------------------------------------------------
// Flash attention, S^T orientation: S^T[s][q] = K·Q^T (A = K rows, B = Q rows).
// Per 16x16 D-tile: lane holds s = st*16+quad*4+r, q = mt*16+l16  =>
// softmax-over-s = in-lane max/sum over 16 regs + shfl_xor(16,32); m/l/alpha
// are per-lane scalars. P^T -> PV B-frag via 32 ds_bpermute (no LDS trip).
// O^T[d][q] = V^T · P: A-frag = transposed sV, out lane: q=mt*16+l16,
// d=dt*16+quad*4+r (contiguous 4-elem bf16 stores).
// Block: 4 waves x 32 q = 128 q rows; s-tiles of 64; heavy qt launched first.
// ---------------------------------------------------------------------------
__global__ __launch_bounds__(256)
void attn(const u16* __restrict__ qph, const u16* __restrict__ qpl,
          const u16* __restrict__ kph, const u16* __restrict__ kpl,
          const u16* __restrict__ vph, u16* __restrict__ yout)
{
  constexpr int VP=72;                  // 64+8 pad for transposed V
  __shared__ u16 sKh[64*64];            // unpadded: global_load_lds dest
  __shared__ u16 sKl[64*64];
  __shared__ u16 sV [64*VP];            // [d][s]

  const int tid=threadIdx.x, wave=tid>>6, lane=tid&63;
  const int quad=lane>>4, l16=lane&15;
  const int qt = (int)(gridDim.x-1-blockIdx.x)>>6;   // descending work
  const int bh = blockIdx.x&63;
  const int b=bh>>4, h=bh&15;
  const int qr0=qt*128+wave*32;

  // Q fragments (stage-1 B-operand): lane q=qr0+mt*16+l16, k=d=ksv*32+quad*8
  bf16x8 qfh[2][2], qfl[2][2];
#pragma unroll
  for(int mt=0;mt<2;mt++)
#pragma unroll
    for(int ksv=0;ksv<2;ksv++){
      size_t off=(size_t)(b*T_+qr0+mt*16+l16)*E_ + h*64 + ksv*32 + quad*8;
      qfh[mt][ksv]=*reinterpret_cast<const bf16x8*>(qph+off);
      qfl[mt][ksv]=*reinterpret_cast<const bf16x8*>(qpl+off);
    }

  float mst[2]={-1e30f,-1e30f}, lst[2]={0.f,0.f};
  f32x4 oacc[2][4];
#pragma unroll
  for(int mt=0;mt<2;mt++)
#pragma unroll
    for(int dt=0;dt<4;dt++) oacc[mt][dt]=zero4();

  const int nkt=2*(qt+1);
  for(int kt=0;kt<nkt;kt++){
    const int s0=kt*64;
    __syncthreads();
    // K hi/lo via async 16B/lane: tile [s][64] row-major
#pragma unroll
    for(int it=0;it<2;it++){
      const int chunk=it*256+tid;
      const size_t off=(size_t)(b*T_+s0+(chunk>>3))*E_ + h*64 + (chunk&7)*8;
      gld16(kph+off, &sKh[(it*256+wave*64)*8]);
      gld16(kpl+off, &sKl[(it*256+wave*64)*8]);
    }
    // V transposed: sV[d][s]
#pragma unroll
    for(int it=0;it<2;it++){
      const int c=it*256+tid, s=c&63, dc=(c>>6)*8;
      u16x8 vv=*reinterpret_cast<const u16x8*>(vph + (size_t)(b*T_+s0+s)*E_ + h*64 + dc);
#pragma unroll
      for(int j=0;j<8;j++) sV[(dc+j)*VP+s]=vv[j];
    }
    __syncthreads();

    if(s0<=qr0+31){
      // ---- S^T = K Q^T, 3-term split ----
      f32x4 sacc[4][2];
#pragma unroll
      for(int st=0;st<4;st++)
#pragma unroll
        for(int mt=0;mt<2;mt++) sacc[st][mt]=zero4();
#pragma unroll
      for(int st=0;st<4;st++)
#pragma unroll
        for(int ksv=0;ksv<2;ksv++){
          bf16x8 kh=*reinterpret_cast<const bf16x8*>(&sKh[(st*16+l16)*64+ksv*32+quad*8]);
          bf16x8 kl=*reinterpret_cast<const bf16x8*>(&sKl[(st*16+l16)*64+ksv*32+quad*8]);
#pragma unroll
          for(int mt=0;mt<2;mt++){
            sacc[st][mt]=mfma16(kh,qfh[mt][ksv],sacc[st][mt]);
            sacc[st][mt]=mfma16(kl,qfh[mt][ksv],sacc[st][mt]);
            sacc[st][mt]=mfma16(kh,qfl[mt][ksv],sacc[st][mt]);
          }
        }
      const bool needmask=(s0+63>qr0);
      u32 pk_[4][2][2];
      // ---- online softmax over s (quirk: *sqrt(D)=8) ----
#pragma unroll
      for(int mt=0;mt<2;mt++){
        const int qrow=qr0+mt*16+l16;
        float mloc=-1e30f;
#pragma unroll
        for(int st=0;st<4;st++)
#pragma unroll
          for(int r=0;r<4;r++){
            float v=sacc[st][mt][r]*8.0f;
            if(needmask && (s0+st*16+quad*4+r>qrow)) v=-1e30f;
            sacc[st][mt][r]=v;
            mloc=fmaxf(mloc,v);
          }
        mloc=fmaxf(mloc,__shfl_xor(mloc,16,64));
        mloc=fmaxf(mloc,__shfl_xor(mloc,32,64));
        const float nm=fmaxf(mst[mt],mloc);
        const float alpha=__expf(mst[mt]-nm);
        mst[mt]=nm;
        float rs=0.f;
#pragma unroll
        for(int st=0;st<4;st++)
#pragma unroll
          for(int r=0;r<4;r++){
            float p=__expf(sacc[st][mt][r]-nm);
            sacc[st][mt][r]=p;
            rs+=p;
          }
        rs+=__shfl_xor(rs,16,64);
        rs+=__shfl_xor(rs,32,64);
        lst[mt]=lst[mt]*alpha+rs;
#pragma unroll
        for(int dt=0;dt<4;dt++) oacc[mt][dt]*=alpha;
#pragma unroll
        for(int st=0;st<4;st++){
          pk_[st][mt][0]=(u32)f2bf(sacc[st][mt][0]) | ((u32)f2bf(sacc[st][mt][1])<<16);
          pk_[st][mt][1]=(u32)f2bf(sacc[st][mt][2]) | ((u32)f2bf(sacc[st][mt][3])<<16);
        }
      }
      // ---- P^T C-layout -> PV B-frag via bpermute; O^T += V^T P ----
      const int srcA=(2*(quad&1))*16+l16, srcB=srcA+16;
      const bool hs=(quad>=2);
#pragma unroll
      for(int ksv=0;ksv<2;ksv++){
        bf16x8 b2[2];
#pragma unroll
        for(int mt=0;mt<2;mt++){
          int e0=__shfl((int)pk_[2*ksv  ][mt][0],srcA,64);
          int g0=__shfl((int)pk_[2*ksv+1][mt][0],srcA,64);
          int e1=__shfl((int)pk_[2*ksv  ][mt][1],srcA,64);
          int g1=__shfl((int)pk_[2*ksv+1][mt][1],srcA,64);
          int e2=__shfl((int)pk_[2*ksv  ][mt][0],srcB,64);
          int g2=__shfl((int)pk_[2*ksv+1][mt][0],srcB,64);
          int e3=__shfl((int)pk_[2*ksv  ][mt][1],srcB,64);
          int g3=__shfl((int)pk_[2*ksv+1][mt][1],srcB,64);
          i32x4 bd={ hs?g0:e0, hs?g1:e1, hs?g2:e2, hs?g3:e3 };
          b2[mt]=*reinterpret_cast<bf16x8*>(&bd);
        }
#pragma unroll
        for(int dt=0;dt<4;dt++){
          bf16x8 va=*reinterpret_cast<const bf16x8*>(&sV[(dt*16+l16)*VP+ksv*32+quad*8]);
#pragma unroll
          for(int mt=0;mt<2;mt++)
            oacc[mt][dt]=mfma16(va,b2[mt],oacc[mt][dt]);
        }
      }
    }
  }
  // ---- y = O/l : lane q=qr0+mt*16+l16, d=dt*16+quad*4+r (4 contiguous) ----
#pragma unroll
  for(int mt=0;mt<2;mt++){
    const float inv=1.0f/lst[mt];
    const size_t rb=(size_t)(b*T_+qr0+mt*16+l16)*E_ + h*64;
#pragma unroll
    for(int dt=0;dt<4;dt++){
      u16x4 o4;
#pragma unroll
      for(int r=0;r<4;r++) o4[r]=f2bf(oacc[mt][dt][r]*inv);
      *reinterpret_cast<u16x4*>(yout + rb + dt*16 + quad*4)=o4;
    }
  }
}

// ---------------------------------------------------------------------------
extern "C" void kernel_launch(void* const* d_in, const int* in_sizes, int n_in,
                              void* d_out, int out_size, void* d_ws, size_t ws_size,
                              hipStream_t stream)
{
  const float* q =(const float*)d_in[0];
  // d_in[1] (k) UNUSED: reference quirk computes kp from qp.
  const float* v =(const float*)d_in[2];
  const float* Wq=(const float*)d_in[3];
  const float* Wk=(const float*)d_in[4];
  const float* Wv=(const float*)d_in[5];
  const float* Wp=(const float*)d_in[6];
  const float* bp=(const float*)d_in[7];
  float* out=(float*)d_out;

  const size_t NE=(size_t)M_*E_;
  u16* ws0=(u16*)d_ws;        // qph
  u16* ws1=ws0+NE;            // qpl
  u16* ws2=ws1+NE;            // qsplit-hi, later kph
  u16* ws3=ws2+NE;            // qsplit-lo, later kpl
  u16* ws4=ws3+NE;            // vpb
  u16* ws5=ws4+NE;            // vb, later ybf
  // weight scratch in d_out (33.5 MB, dead until final GEMM which reads fp32 Wp)
  const size_t WE=(size_t)E_*E_;
  u16* wqh=(u16*)d_out;
  u16* wql=wqh+WE;
  u16* wkh=wql+WE;
  u16* wkl=wkh+WE;
  u16* wvb=wkl+WE;

  dim3 blk(256);
  cvt_a<<<dim3(NE/1024,2), blk, 0, stream>>>(q, v, ws2, ws3, ws5);
  cvt_w<<<dim3(WE/1024,3), blk, 0, stream>>>(Wq, Wk, Wv, wqh, wql, wkh, wkl, wvb);

  dim3 g(E_/128, M_/128);
  // qp = qsplit @ Wq^T (split in, split out)
  gemm<1,1,0,0><<<g, blk, 0, stream>>>(ws2, ws3, wqh, wql, nullptr, nullptr, ws0, ws1, nullptr);
  // kp = qpsplit @ Wk^T
  gemm<1,1,0,0><<<g, blk, 0, stream>>>(ws0, ws1, wkh, wkl, nullptr, nullptr, ws2, ws3, nullptr);
  // vp = vb @ Wv^T (plain)
  gemm<0,0,0,1><<<g, blk, 0, stream>>>(ws5, nullptr, wvb, nullptr, nullptr, nullptr, ws4, nullptr, nullptr);
  // attention -> ybf (overwrites vb)
  attn<<<dim3(16*64), blk, 0, stream>>>(ws0, ws1, ws2, ws3, ws4, ws5);
  // out = ybf @ Wp^T + bp (W staged from fp32 in-loop; d_out scratch now dead)
  gemm<0,0,1,2><<<g, blk, 0, stream>>>(ws5, nullptr, nullptr, nullptr, Wp, bp, nullptr, nullptr, out);
}

// Round 3
// 459.892 us; speedup vs baseline: 1.5439x; 1.0539x over previous
//
#include <hip/hip_runtime.h>

// ---------------------------------------------------------------------------
// qp = q@Wq.T ; kp = qp@Wk.T (quirk) ; vp = v@Wv.T
// att = softmax(causal(q k^T * sqrt(D))) ; y = att v ; out = y@Wp.T + bp
// Score path split bf16 (hi/lo, 3-term MFMA). Round-3: interleaved hi/lo
// format + XOR chunk swizzle in LDS (kills the pitch%32==0 bank conflicts
// under global_load_lds), BK=64 plain GEMMs, exp2f-fused softmax, v_perm
// bf16 packing.
// ws layout (6*NE u16 proven): [0,2NE)=qsplit_i then kp_i, [2NE,4NE)=qp_i,
// [4NE,5NE)=vpb, [5NE,6NE)=ybf. d_out scratch: wq_i,wk_i,wv_b,vb (27MB<33.5).
// ---------------------------------------------------------------------------

typedef unsigned short u16;
typedef unsigned int   u32;
typedef __attribute__((ext_vector_type(8))) __bf16 bf16x8;
typedef __attribute__((ext_vector_type(8))) u16    u16x8;
typedef __attribute__((ext_vector_type(4))) u16    u16x4;
typedef __attribute__((ext_vector_type(4))) float  f32x4;
typedef __attribute__((ext_vector_type(4))) int    i32x4;

#define DEV static __device__ __forceinline__

DEV u16 f2bf(float x){ union{float f;u32 u;}v; v.f=x; u32 r=v.u+0x7fffu+((v.u>>16)&1u); return (u16)(r>>16); }
DEV float bf2f(u16 b){ union{u32 u;float f;}v; v.u=((u32)b)<<16; return v.f; }
DEV f32x4 zero4(){ f32x4 z={0.f,0.f,0.f,0.f}; return z; }
DEV f32x4 mfma16(bf16x8 a, bf16x8 b, f32x4 c){ return __builtin_amdgcn_mfma_f32_16x16x32_bf16(a,b,c,0,0,0); }
DEV void gld16(const u16* g, u16* l){
  __builtin_amdgcn_global_load_lds((const __attribute__((address_space(1))) u32*)g,
                                   (__attribute__((address_space(3))) u32*)l, 16, 0, 0);
}
// pack hi16(a),hi16(b) -> u32 (b in high half), round-half-up via +0x8000
DEV u32 pkbf(float a, float b){
  union{float f;u32 u;}x,y; x.f=a; y.f=b;
  return __builtin_amdgcn_perm(y.u+0x8000u, x.u+0x8000u, 0x07060302u);
}

constexpr int B_=4, T_=2048, E_=1024;
constexpr int M_=B_*T_;                  // 8192
constexpr float L2E8 = 11.5415603f;      // 8/ln2 (quirk scale folded into exp2)

// ---------------------------------------------------------------------------
// cvt: j==0: q -> interleaved hi/lo split (row len 2E, chunks [h0 l0 h1 l1..])
//      j==1: v -> plain bf16
// ---------------------------------------------------------------------------
__global__ __launch_bounds__(256)
void cvt_a(const float* __restrict__ q, const float* __restrict__ v,
           u16* __restrict__ qi, u16* __restrict__ vb)
{
  const int j=blockIdx.y;
  const size_t e=((size_t)blockIdx.x*256+threadIdx.x)*8;
  const float* s=(j==0)?q:v;
  f32x4 x0=*reinterpret_cast<const f32x4*>(s+e);
  f32x4 x1=*reinterpret_cast<const f32x4*>(s+e+4);
  u16x8 h,l;
#pragma unroll
  for(int t=0;t<4;t++){
    u16 hh=f2bf(x0[t]); h[t]=hh; l[t]=f2bf(x0[t]-bf2f(hh));
    u16 h2=f2bf(x1[t]); h[t+4]=h2; l[t+4]=f2bf(x1[t]-bf2f(h2));
  }
  if(j==0){
    const size_t row=e>>10, k=e&1023;
    u16* d=qi + row*2048 + (k>>3)*16;
    *reinterpret_cast<u16x8*>(d)=h;
    *reinterpret_cast<u16x8*>(d+8)=l;
  } else {
    *reinterpret_cast<u16x8*>(vb+e)=h;
  }
}

__global__ __launch_bounds__(256)
void cvt_w(const float* __restrict__ Wq, const float* __restrict__ Wk, const float* __restrict__ Wv,
           u16* __restrict__ wqi, u16* __restrict__ wki, u16* __restrict__ wvb)
{
  const int j=blockIdx.y;
  const size_t e=((size_t)blockIdx.x*256+threadIdx.x)*8;
  const float* s=(j==0)?Wq:(j==1)?Wk:Wv;
  f32x4 x0=*reinterpret_cast<const f32x4*>(s+e);
  f32x4 x1=*reinterpret_cast<const f32x4*>(s+e+4);
  u16x8 h,l;
#pragma unroll
  for(int t=0;t<4;t++){
    u16 hh=f2bf(x0[t]); h[t]=hh; l[t]=f2bf(x0[t]-bf2f(hh));
    u16 h2=f2bf(x1[t]); h[t+4]=h2; l[t+4]=f2bf(x1[t]-bf2f(h2));
  }
  if(j==2){ *reinterpret_cast<u16x8*>(wvb+e)=h; return; }
  u16* base=(j==0)?wqi:wki;
  const size_t row=e>>10, k=e&1023;
  u16* d=base + row*2048 + (k>>3)*16;
  *reinterpret_cast<u16x8*>(d)=h;
  *reinterpret_cast<u16x8*>(d+8)=l;
}

// ---------------------------------------------------------------------------
// GEMM C[M,N]=A[M,K]@W[N,K]^T. 128x128 tile, 4 waves (2x2 of 64x64).
// LDS tiles: 128 rows x 8 chunks(16B), XOR-swizzled: phys = logical ^ (row&7).
// SPLIT: interleaved hi/lo operands, BK=32, 3-term MFMA (48/iter x32).
// PLAIN: BK=64 (32 MFMA/iter x16). WF32: B staged from fp32, pitch 68 (pad).
// OMODE: 0 split-interleaved out, 1 plain bf16 out, 2 fp32+bias.
// ---------------------------------------------------------------------------
template<int SPLIT,int WF32,int OMODE>
__global__ __launch_bounds__(256)
void gemm(const u16* __restrict__ Ag, const u16* __restrict__ Bg,
          const float* __restrict__ Wf, const float* __restrict__ bias,
          u16* __restrict__ Ob, float* __restrict__ Of)
{
  __shared__ u16 sA[128*64];
  __shared__ u16 sB[WF32 ? 128*68 : 128*64];

  const int tid=threadIdx.x, wave=tid>>6, lane=tid&63;
  const int quad=lane>>4, l16=lane&15, sw=l16&7;
  const int wm=(wave>>1)*64, wn=(wave&1)*64;
  const int n0=blockIdx.x*128, m0=blockIdx.y*128;
  constexpr int KSTEP = SPLIT?32:64;

  f32x4 acc[4][4];
#pragma unroll
  for(int i=0;i<4;i++)
#pragma unroll
    for(int j=0;j<4;j++) acc[i][j]=zero4();

  for(int k0=0;k0<E_;k0+=KSTEP){
    // ---- A tile: 1024 chunks, swizzled ----
#pragma unroll
    for(int it=0;it<4;it++){
      const int c=it*256+tid, row=c>>3, j=(c&7)^(row&7);
      const u16* ga = SPLIT ? Ag + (size_t)(m0+row)*2048 + (size_t)(k0>>3)*16 + j*8
                            : Ag + (size_t)(m0+row)*1024 + k0 + j*8;
      gld16(ga, &sA[(it*256+wave*64)*8]);
    }
    // ---- B tile ----
    if(!WF32){
#pragma unroll
      for(int it=0;it<4;it++){
        const int c=it*256+tid, row=c>>3, j=(c&7)^(row&7);
        const u16* gb = SPLIT ? Bg + (size_t)(n0+row)*2048 + (size_t)(k0>>3)*16 + j*8
                              : Bg + (size_t)(n0+row)*1024 + k0 + j*8;
        gld16(gb, &sB[(it*256+wave*64)*8]);
      }
    } else {
#pragma unroll
      for(int it=0;it<8;it++){
        const int idx=it*256+tid, row=idx>>4, col=(idx&15)*4;
        f32x4 w=*reinterpret_cast<const f32x4*>(Wf + (size_t)(n0+row)*1024 + k0+col);
        u16x4 hh;
#pragma unroll
        for(int t=0;t<4;t++) hh[t]=f2bf(w[t]);
        *reinterpret_cast<u16x4*>(&sB[row*68+col])=hh;
      }
    }
    __syncthreads();

    if(SPLIT){
      bf16x8 ahh[4],ahl[4],bhh[4],bhl[4];
#pragma unroll
      for(int i=0;i<4;i++){
        const u16* pa=&sA[(wm+i*16+l16)*64];
        const u16* pb=&sB[(wn+i*16+l16)*64];
        ahh[i]=*reinterpret_cast<const bf16x8*>(&pa[((2*quad  )^sw)*8]);
        ahl[i]=*reinterpret_cast<const bf16x8*>(&pa[((2*quad+1)^sw)*8]);
        bhh[i]=*reinterpret_cast<const bf16x8*>(&pb[((2*quad  )^sw)*8]);
        bhl[i]=*reinterpret_cast<const bf16x8*>(&pb[((2*quad+1)^sw)*8]);
      }
#pragma unroll
      for(int i=0;i<4;i++)
#pragma unroll
        for(int j=0;j<4;j++){
          acc[i][j]=mfma16(ahh[i],bhh[j],acc[i][j]);
          acc[i][j]=mfma16(ahh[i],bhl[j],acc[i][j]);
          acc[i][j]=mfma16(ahl[i],bhh[j],acc[i][j]);
        }
    } else {
#pragma unroll
      for(int kk=0;kk<2;kk++){
        bf16x8 a[4],b[4];
#pragma unroll
        for(int i=0;i<4;i++){
          a[i]=*reinterpret_cast<const bf16x8*>(&sA[(wm+i*16+l16)*64 + (((kk*4+quad)^sw)*8)]);
          b[i]= WF32 ? *reinterpret_cast<const bf16x8*>(&sB[(wn+i*16+l16)*68 + kk*32+quad*8])
                     : *reinterpret_cast<const bf16x8*>(&sB[(wn+i*16+l16)*64 + (((kk*4+quad)^sw)*8)]);
        }
#pragma unroll
        for(int i=0;i<4;i++)
#pragma unroll
          for(int j=0;j<4;j++)
            acc[i][j]=mfma16(a[i],b[j],acc[i][j]);
      }
    }
    __syncthreads();
  }

  // epilogue: D row=quad*4+r, col=l16 (verified)
#pragma unroll
  for(int i=0;i<4;i++)
#pragma unroll
    for(int j=0;j<4;j++){
      const int col=n0+wn+j*16+l16;
#pragma unroll
      for(int r=0;r<4;r++){
        const int row=m0+wm+i*16+quad*4+r;
        float v=acc[i][j][r];
        if(OMODE==2)      Of[(size_t)row*E_+col]=v+bias[col];
        else if(OMODE==1) Ob[(size_t)row*E_+col]=f2bf(v);
        else {
          u16 hh=f2bf(v);
          const size_t base=(size_t)row*2048 + (size_t)(col>>3)*16 + (col&7);
          Ob[base]=hh; Ob[base+8]=f2bf(v-bf2f(hh));
        }
      }
    }
}

// ---------------------------------------------------------------------------
// Flash attention, S^T orientation (round-2 verified). K interleaved hi/lo in
// one swizzled LDS tile (64 s-rows x 16 chunks, phys = j ^ (row&7)); V
// transposed with pitch 68 (34 dw = 2 mod 32 -> 2-way max). exp2f-fused
// softmax with the x8 quirk folded into the exponent; P packed via v_perm.
// ---------------------------------------------------------------------------
__global__ __launch_bounds__(256)
void attn(const u16* __restrict__ qpi, const u16* __restrict__ kpi,
          const u16* __restrict__ vph, u16* __restrict__ yout)
{
  constexpr int VP=68;
  __shared__ u16 sK[64*128];
  __shared__ u16 sV[64*VP];

  const int tid=threadIdx.x, wave=tid>>6, lane=tid&63;
  const int quad=lane>>4, l16=lane&15, sw=l16&7;
  const int qt=(int)(gridDim.x-1-blockIdx.x)>>6;   // descending work
  const int bh=blockIdx.x&63;
  const int b=bh>>4, h=bh&15;
  const int qr0=qt*128+wave*32;

  // Q fragments hi/lo from interleaved qp
  bf16x8 qfh[2][2], qfl[2][2];
#pragma unroll
  for(int mt=0;mt<2;mt++)
#pragma unroll
    for(int ksv=0;ksv<2;ksv++){
      const size_t off=(size_t)(b*T_+qr0+mt*16+l16)*2048 + h*128 + (ksv*4+quad)*16;
      qfh[mt][ksv]=*reinterpret_cast<const bf16x8*>(qpi+off);
      qfl[mt][ksv]=*reinterpret_cast<const bf16x8*>(qpi+off+8);
    }

  float mst[2]={-1e30f,-1e30f}, lst[2]={0.f,0.f};
  f32x4 oacc[2][4];
#pragma unroll
  for(int mt=0;mt<2;mt++)
#pragma unroll
    for(int dt=0;dt<4;dt++) oacc[mt][dt]=zero4();

  const int nkt=2*(qt+1);
  for(int kt=0;kt<nkt;kt++){
    const int s0=kt*64;
    __syncthreads();
    // K tile: 1024 chunks (64 rows x 16), swizzled
#pragma unroll
    for(int it=0;it<4;it++){
      const int c=it*256+tid, row=c>>4, j=(c&15)^(row&7);
      gld16(kpi + (size_t)(b*T_+s0+row)*2048 + h*128 + j*8,
            &sK[(it*256+wave*64)*8]);
    }
    // V transposed: sV[d][s]
#pragma unroll
    for(int it=0;it<2;it++){
      const int c=it*256+tid, s=c&63, dc=(c>>6)*8;
      u16x8 vv=*reinterpret_cast<const u16x8*>(vph + (size_t)(b*T_+s0+s)*1024 + h*64 + dc);
#pragma unroll
      for(int j=0;j<8;j++) sV[(dc+j)*VP+s]=vv[j];
    }
    __syncthreads();

    if(s0<=qr0+31){
      // ---- S^T = K Q^T, 3-term split ----
      f32x4 sacc[4][2];
#pragma unroll
      for(int st=0;st<4;st++)
#pragma unroll
        for(int mt=0;mt<2;mt++) sacc[st][mt]=zero4();
#pragma unroll
      for(int st=0;st<4;st++)
#pragma unroll
        for(int ksv=0;ksv<2;ksv++){
          const u16* pk=&sK[(st*16+l16)*128];
          bf16x8 kh=*reinterpret_cast<const bf16x8*>(&pk[((2*(ksv*4+quad)  )^sw)*8]);
          bf16x8 kl=*reinterpret_cast<const bf16x8*>(&pk[((2*(ksv*4+quad)+1)^sw)*8]);
#pragma unroll
          for(int mt=0;mt<2;mt++){
            sacc[st][mt]=mfma16(kh,qfh[mt][ksv],sacc[st][mt]);
            sacc[st][mt]=mfma16(kl,qfh[mt][ksv],sacc[st][mt]);
            sacc[st][mt]=mfma16(kh,qfl[mt][ksv],sacc[st][mt]);
          }
        }
      const bool needmask=(s0+63>qr0);
      u32 pk_[4][2][2];
      // ---- online softmax over s; raw logits, x8 folded into exp2 ----
#pragma unroll
      for(int mt=0;mt<2;mt++){
        const int qrow=qr0+mt*16+l16;
        float mloc=-1e30f;
#pragma unroll
        for(int st=0;st<4;st++)
#pragma unroll
          for(int r=0;r<4;r++){
            float v=sacc[st][mt][r];
            if(needmask && (s0+st*16+quad*4+r>qrow)) v=-1e30f;
            sacc[st][mt][r]=v;
            mloc=fmaxf(mloc,v);
          }
        mloc=fmaxf(mloc,__shfl_xor(mloc,16,64));
        mloc=fmaxf(mloc,__shfl_xor(mloc,32,64));
        const float nm=fmaxf(mst[mt],mloc);
        const float alpha=exp2f((mst[mt]-nm)*L2E8);
        mst[mt]=nm;
        const float cexp=nm*L2E8;
        float rs=0.f;
#pragma unroll
        for(int st=0;st<4;st++)
#pragma unroll
          for(int r=0;r<4;r++){
            float p=exp2f(__builtin_fmaf(sacc[st][mt][r],L2E8,-cexp));
            sacc[st][mt][r]=p;
            rs+=p;
          }
        rs+=__shfl_xor(rs,16,64);
        rs+=__shfl_xor(rs,32,64);
        lst[mt]=lst[mt]*alpha+rs;
#pragma unroll
        for(int dt=0;dt<4;dt++) oacc[mt][dt]*=alpha;
#pragma unroll
        for(int st=0;st<4;st++){
          pk_[st][mt][0]=pkbf(sacc[st][mt][0],sacc[st][mt][1]);
          pk_[st][mt][1]=pkbf(sacc[st][mt][2],sacc[st][mt][3]);
        }
      }
      // ---- P^T C-layout -> PV B-frag via shfl; O^T += V^T P ----
      const int srcA=(2*(quad&1))*16+l16, srcB=srcA+16;
      const bool hs=(quad>=2);
#pragma unroll
      for(int ksv=0;ksv<2;ksv++){
        bf16x8 b2[2];
#pragma unroll
        for(int mt=0;mt<2;mt++){
          int e0=__shfl((int)pk_[2*ksv  ][mt][0],srcA,64);
          int g0=__shfl((int)pk_[2*ksv+1][mt][0],srcA,64);
          int e1=__shfl((int)pk_[2*ksv  ][mt][1],srcA,64);
          int g1=__shfl((int)pk_[2*ksv+1][mt][1],srcA,64);
          int e2=__shfl((int)pk_[2*ksv  ][mt][0],srcB,64);
          int g2=__shfl((int)pk_[2*ksv+1][mt][0],srcB,64);
          int e3=__shfl((int)pk_[2*ksv  ][mt][1],srcB,64);
          int g3=__shfl((int)pk_[2*ksv+1][mt][1],srcB,64);
          i32x4 bd={ hs?g0:e0, hs?g1:e1, hs?g2:e2, hs?g3:e3 };
          b2[mt]=*reinterpret_cast<bf16x8*>(&bd);
        }
#pragma unroll
        for(int dt=0;dt<4;dt++){
          bf16x8 va=*reinterpret_cast<const bf16x8*>(&sV[(dt*16+l16)*VP+ksv*32+quad*8]);
#pragma unroll
          for(int mt=0;mt<2;mt++)
            oacc[mt][dt]=mfma16(va,b2[mt],oacc[mt][dt]);
        }
      }
    }
  }
  // ---- y = O/l ----
#pragma unroll
  for(int mt=0;mt<2;mt++){
    const float inv=1.0f/lst[mt];
    const size_t rb=(size_t)(b*T_+qr0+mt*16+l16)*1024 + h*64;
#pragma unroll
    for(int dt=0;dt<4;dt++){
      u16x4 o4;
#pragma unroll
      for(int r=0;r<4;r++) o4[r]=f2bf(oacc[mt][dt][r]*inv);
      *reinterpret_cast<u16x4*>(yout + rb + dt*16 + quad*4)=o4;
    }
  }
}

// ---------------------------------------------------------------------------
extern "C" void kernel_launch(void* const* d_in, const int* in_sizes, int n_in,
                              void* d_out, int out_size, void* d_ws, size_t ws_size,
                              hipStream_t stream)
{
  const float* q =(const float*)d_in[0];
  // d_in[1] (k) UNUSED: reference quirk computes kp from qp.
  const float* v =(const float*)d_in[2];
  const float* Wq=(const float*)d_in[3];
  const float* Wk=(const float*)d_in[4];
  const float* Wv=(const float*)d_in[5];
  const float* Wp=(const float*)d_in[6];
  const float* bp=(const float*)d_in[7];
  float* out=(float*)d_out;

  const size_t NE=(size_t)M_*E_;          // 8.39M
  const size_t WE=(size_t)E_*E_;          // 1.05M
  u16* wsv=(u16*)d_ws;
  u16* qsl_i=wsv;                         // [0,2NE): qsplit_i, later kp_i
  u16* qp_i =wsv+2*NE;                    // [2NE,4NE)
  u16* kp_i =wsv;                         // alias (qsplit dead after G1)
  u16* vpb  =wsv+4*NE;                    // [4NE,5NE)
  u16* ybf  =wsv+5*NE;                    // [5NE,6NE)
  u16* og   =(u16*)d_out;                 // scratch until final GEMM
  u16* wq_i =og;                          // 2WE
  u16* wk_i =og+2*WE;                     // 2WE
  u16* wv_b =og+4*WE;                     // WE
  u16* vb   =og+5*WE;                     // NE  (total 13.6M u16 < 16.78M)

  dim3 blk(256);
  cvt_a<<<dim3(NE/2048,2), blk, 0, stream>>>(q, v, qsl_i, vb);
  cvt_w<<<dim3(WE/2048,3), blk, 0, stream>>>(Wq, Wk, Wv, wq_i, wk_i, wv_b);

  dim3 g(E_/128, M_/128);
  gemm<1,0,0><<<g, blk, 0, stream>>>(qsl_i, wq_i, nullptr, nullptr, qp_i, nullptr);
  gemm<1,0,0><<<g, blk, 0, stream>>>(qp_i,  wk_i, nullptr, nullptr, kp_i, nullptr);
  gemm<0,0,1><<<g, blk, 0, stream>>>(vb,    wv_b, nullptr, nullptr, vpb,  nullptr);
  attn<<<dim3(1024), blk, 0, stream>>>(qp_i, kp_i, vpb, ybf);
  gemm<0,1,2><<<g, blk, 0, stream>>>(ybf, nullptr, Wp, bp, nullptr, out);
}

// Round 4
// 428.114 us; speedup vs baseline: 1.6585x; 1.0742x over previous
//
#include <hip/hip_runtime.h>

// ---------------------------------------------------------------------------
// qp = q@Wq.T ; kp = qp@Wk.T (quirk) ; vp = v@Wv.T
// att = softmax(causal(q k^T * sqrt(D))) ; y = att v ; out = y@Wp.T + bp
// Score path split bf16 (hi/lo interleaved, 3-term MFMA) -> ~fp32 logits.
// Round-4: V produced pre-transposed (vpT = Wv @ v^T) so attention stages
// V^T via global_load_lds like K (kills the in-kernel LDS transpose);
// split GEMMs BK=64 (half the barrier drains, LDS 64K = grid-imposed
// 2 blocks/CU anyway); Wp pre-converted to bf16 (dead qp region) so the
// out-proj GEMM is pure gld16.
// ws (6NE u16 = 96 MiB proven): [0,2NE) qsl_i -> kp_i ; [2NE,4NE) qp_i -> wp_b
// [4NE,5NE) vpT ; [5NE,6NE) ybf. d_out scratch (dead before out-proj):
// wq_i 2WE | wk_i 2WE | wv_b WE | vb NE  (27.3 MB < 33.5).
// ---------------------------------------------------------------------------

typedef unsigned short u16;
typedef unsigned int   u32;
typedef __attribute__((ext_vector_type(8))) __bf16 bf16x8;
typedef __attribute__((ext_vector_type(8))) u16    u16x8;
typedef __attribute__((ext_vector_type(4))) u16    u16x4;
typedef __attribute__((ext_vector_type(4))) float  f32x4;
typedef __attribute__((ext_vector_type(4))) int    i32x4;

#define DEV static __device__ __forceinline__

DEV u16 f2bf(float x){ union{float f;u32 u;}v; v.f=x; u32 r=v.u+0x7fffu+((v.u>>16)&1u); return (u16)(r>>16); }
DEV float bf2f(u16 b){ union{u32 u;float f;}v; v.u=((u32)b)<<16; return v.f; }
DEV f32x4 zero4(){ f32x4 z={0.f,0.f,0.f,0.f}; return z; }
DEV f32x4 mfma16(bf16x8 a, bf16x8 b, f32x4 c){ return __builtin_amdgcn_mfma_f32_16x16x32_bf16(a,b,c,0,0,0); }
DEV void gld16(const u16* g, u16* l){
  __builtin_amdgcn_global_load_lds((const __attribute__((address_space(1))) u32*)g,
                                   (__attribute__((address_space(3))) u32*)l, 16, 0, 0);
}
DEV u32 pkbf(float a, float b){
  union{float f;u32 u;}x,y; x.f=a; y.f=b;
  return __builtin_amdgcn_perm(y.u+0x8000u, x.u+0x8000u, 0x07060302u);
}

constexpr int B_=4, T_=2048, E_=1024;
constexpr int M_=B_*T_;                  // 8192
constexpr float L2E8 = 11.5415603f;      // 8/ln2 (quirk scale folded into exp2)

// ---------------------------------------------------------------------------
__global__ __launch_bounds__(256)
void cvt_a(const float* __restrict__ q, const float* __restrict__ v,
           u16* __restrict__ qi, u16* __restrict__ vb)
{
  const int j=blockIdx.y;
  const size_t e=((size_t)blockIdx.x*256+threadIdx.x)*8;
  const float* s=(j==0)?q:v;
  f32x4 x0=*reinterpret_cast<const f32x4*>(s+e);
  f32x4 x1=*reinterpret_cast<const f32x4*>(s+e+4);
  u16x8 h,l;
#pragma unroll
  for(int t=0;t<4;t++){
    u16 hh=f2bf(x0[t]); h[t]=hh; l[t]=f2bf(x0[t]-bf2f(hh));
    u16 h2=f2bf(x1[t]); h[t+4]=h2; l[t+4]=f2bf(x1[t]-bf2f(h2));
  }
  if(j==0){
    const size_t row=e>>10, k=e&1023;
    u16* d=qi + row*2048 + (k>>3)*16;
    *reinterpret_cast<u16x8*>(d)=h;
    *reinterpret_cast<u16x8*>(d+8)=l;
  } else {
    *reinterpret_cast<u16x8*>(vb+e)=h;
  }
}

__global__ __launch_bounds__(256)
void cvt_w(const float* __restrict__ Wq, const float* __restrict__ Wk, const float* __restrict__ Wv,
           u16* __restrict__ wqi, u16* __restrict__ wki, u16* __restrict__ wvb)
{
  const int j=blockIdx.y;
  const size_t e=((size_t)blockIdx.x*256+threadIdx.x)*8;
  const float* s=(j==0)?Wq:(j==1)?Wk:Wv;
  f32x4 x0=*reinterpret_cast<const f32x4*>(s+e);
  f32x4 x1=*reinterpret_cast<const f32x4*>(s+e+4);
  u16x8 h,l;
#pragma unroll
  for(int t=0;t<4;t++){
    u16 hh=f2bf(x0[t]); h[t]=hh; l[t]=f2bf(x0[t]-bf2f(hh));
    u16 h2=f2bf(x1[t]); h[t+4]=h2; l[t+4]=f2bf(x1[t]-bf2f(h2));
  }
  if(j==2){ *reinterpret_cast<u16x8*>(wvb+e)=h; return; }
  u16* base=(j==0)?wqi:wki;
  const size_t row=e>>10, k=e&1023;
  u16* d=base + row*2048 + (k>>3)*16;
  *reinterpret_cast<u16x8*>(d)=h;
  *reinterpret_cast<u16x8*>(d+8)=l;
}

__global__ __launch_bounds__(256)
void cvt_p(const float* __restrict__ Wp, u16* __restrict__ wpb)
{
  const size_t e=((size_t)blockIdx.x*256+threadIdx.x)*8;
  f32x4 x0=*reinterpret_cast<const f32x4*>(Wp+e);
  f32x4 x1=*reinterpret_cast<const f32x4*>(Wp+e+4);
  u16x8 h;
#pragma unroll
  for(int t=0;t<4;t++){ h[t]=f2bf(x0[t]); h[t+4]=f2bf(x1[t]); }
  *reinterpret_cast<u16x8*>(wpb+e)=h;
}

// ---------------------------------------------------------------------------
// GEMM C[M',N'] = A[M',K] @ B[N',K]^T, K=1024, BK=64. 128x128 tile, 4 waves
// (2x2 of 64x64). All staging via global_load_lds with XOR chunk swizzle
// phys = logical ^ (row&7).
// SPLIT: interleaved hi/lo operands (row = 2048 u16), 96 MFMA/iter.
// OMODE: 0 split-interleaved out ; 1 plain bf16 out (ldc) ; 2 fp32+bias (ldc).
// ---------------------------------------------------------------------------
template<int SPLIT,int OMODE>
__global__ __launch_bounds__(256)
void gemm(const u16* __restrict__ Ag, const u16* __restrict__ Bg,
          const float* __restrict__ bias,
          u16* __restrict__ Ob, float* __restrict__ Of, int ldc)
{
  __shared__ u16 sA[SPLIT?128*128:128*64];
  __shared__ u16 sB[SPLIT?128*128:128*64];

  const int tid=threadIdx.x, wave=tid>>6, lane=tid&63;
  const int quad=lane>>4, l16=lane&15, sw=l16&7;
  const int wm=(wave>>1)*64, wn=(wave&1)*64;
  const int n0=blockIdx.x*128, m0=blockIdx.y*128;

  f32x4 acc[4][4];
#pragma unroll
  for(int i=0;i<4;i++)
#pragma unroll
    for(int j=0;j<4;j++) acc[i][j]=zero4();

  for(int k0=0;k0<E_;k0+=64){
    if(SPLIT){
      // 2048 chunks each (128 rows x 16), swizzled
#pragma unroll
      for(int it=0;it<8;it++){
        const int c=it*256+tid, row=c>>4, j=(c&15)^(row&7);
        gld16(Ag + (size_t)(m0+row)*2048 + k0*2 + j*8, &sA[(it*256+wave*64)*8]);
      }
#pragma unroll
      for(int it=0;it<8;it++){
        const int c=it*256+tid, row=c>>4, j=(c&15)^(row&7);
        gld16(Bg + (size_t)(n0+row)*2048 + k0*2 + j*8, &sB[(it*256+wave*64)*8]);
      }
    } else {
      // 1024 chunks each (128 rows x 8), swizzled
#pragma unroll
      for(int it=0;it<4;it++){
        const int c=it*256+tid, row=c>>3, j=(c&7)^(row&7);
        gld16(Ag + (size_t)(m0+row)*1024 + k0 + j*8, &sA[(it*256+wave*64)*8]);
      }
#pragma unroll
      for(int it=0;it<4;it++){
        const int c=it*256+tid, row=c>>3, j=(c&7)^(row&7);
        gld16(Bg + (size_t)(n0+row)*1024 + k0 + j*8, &sB[(it*256+wave*64)*8]);
      }
    }
    __syncthreads();

#pragma unroll
    for(int kk=0;kk<2;kk++){
      if(SPLIT){
        bf16x8 ahh[4],ahl[4],bhh[4],bhl[4];
#pragma unroll
        for(int i=0;i<4;i++){
          const u16* pa=&sA[(wm+i*16+l16)*128];
          const u16* pb=&sB[(wn+i*16+l16)*128];
          const int ch=2*(kk*4+quad);
          ahh[i]=*reinterpret_cast<const bf16x8*>(&pa[((ch  )^sw)*8]);
          ahl[i]=*reinterpret_cast<const bf16x8*>(&pa[((ch+1)^sw)*8]);
          bhh[i]=*reinterpret_cast<const bf16x8*>(&pb[((ch  )^sw)*8]);
          bhl[i]=*reinterpret_cast<const bf16x8*>(&pb[((ch+1)^sw)*8]);
        }
#pragma unroll
        for(int i=0;i<4;i++)
#pragma unroll
          for(int j=0;j<4;j++){
            acc[i][j]=mfma16(ahh[i],bhh[j],acc[i][j]);
            acc[i][j]=mfma16(ahh[i],bhl[j],acc[i][j]);
            acc[i][j]=mfma16(ahl[i],bhh[j],acc[i][j]);
          }
      } else {
        bf16x8 a[4],b[4];
#pragma unroll
        for(int i=0;i<4;i++){
          a[i]=*reinterpret_cast<const bf16x8*>(&sA[(wm+i*16+l16)*64 + (((kk*4+quad)^sw)*8)]);
          b[i]=*reinterpret_cast<const bf16x8*>(&sB[(wn+i*16+l16)*64 + (((kk*4+quad)^sw)*8)]);
        }
#pragma unroll
        for(int i=0;i<4;i++)
#pragma unroll
          for(int j=0;j<4;j++)
            acc[i][j]=mfma16(a[i],b[j],acc[i][j]);
      }
    }
    __syncthreads();
  }

  // epilogue: D row=quad*4+r, col=l16 (verified)
#pragma unroll
  for(int i=0;i<4;i++)
#pragma unroll
    for(int j=0;j<4;j++){
      const int col=n0+wn+j*16+l16;
#pragma unroll
      for(int r=0;r<4;r++){
        const int row=m0+wm+i*16+quad*4+r;
        float v=acc[i][j][r];
        if(OMODE==2)      Of[(size_t)row*ldc+col]=v+bias[col];
        else if(OMODE==1) Ob[(size_t)row*ldc+col]=f2bf(v);
        else {
          u16 hh=f2bf(v);
          const size_t base=(size_t)row*2048 + (size_t)(col>>3)*16 + (col&7);
          Ob[base]=hh; Ob[base+8]=f2bf(v-bf2f(hh));
        }
      }
    }
}

// ---------------------------------------------------------------------------
// Flash attention, S^T orientation. K (interleaved hi/lo) AND V^T both staged
// via global_load_lds with XOR swizzle — no in-kernel transpose. V^T comes
// from vpT[e][b*T+t]. Softmax: exp2-fused with x8 quirk in exponent; l-sum
// cross-quad reduction deferred to epilogue.
// ---------------------------------------------------------------------------
__global__ __launch_bounds__(256)
void attn(const u16* __restrict__ qpi, const u16* __restrict__ kpi,
          const u16* __restrict__ vpT, u16* __restrict__ yout)
{
  __shared__ u16 sK [64*128];           // 16 KB
  __shared__ u16 sVT[64*64];            // 8 KB, [d][s] swizzled

  const int tid=threadIdx.x, wave=tid>>6, lane=tid&63;
  const int quad=lane>>4, l16=lane&15, sw=l16&7;
  const int qt=(int)(gridDim.x-1-blockIdx.x)>>6;   // descending work
  const int bh=blockIdx.x&63;
  const int b=bh>>4, h=bh&15;
  const int qr0=qt*128+wave*32;

  bf16x8 qfh[2][2], qfl[2][2];
#pragma unroll
  for(int mt=0;mt<2;mt++)
#pragma unroll
    for(int ksv=0;ksv<2;ksv++){
      const size_t off=(size_t)(b*T_+qr0+mt*16+l16)*2048 + h*128 + (ksv*4+quad)*16;
      qfh[mt][ksv]=*reinterpret_cast<const bf16x8*>(qpi+off);
      qfl[mt][ksv]=*reinterpret_cast<const bf16x8*>(qpi+off+8);
    }

  float mst[2]={-1e30f,-1e30f}, lst[2]={0.f,0.f};
  f32x4 oacc[2][4];
#pragma unroll
  for(int mt=0;mt<2;mt++)
#pragma unroll
    for(int dt=0;dt<4;dt++) oacc[mt][dt]=zero4();

  const int nkt=2*(qt+1);
  for(int kt=0;kt<nkt;kt++){
    const int s0=kt*64;
    __syncthreads();
    // K tile: 1024 chunks (64 rows x 16), swizzled
#pragma unroll
    for(int it=0;it<4;it++){
      const int c=it*256+tid, row=c>>4, j=(c&15)^(row&7);
      gld16(kpi + (size_t)(b*T_+s0+row)*2048 + h*128 + j*8,
            &sK[(it*256+wave*64)*8]);
    }
    // V^T tile: 512 chunks (64 d-rows x 8), swizzled, from vpT
#pragma unroll
    for(int it=0;it<2;it++){
      const int c=it*256+tid, row=c>>3, j=(c&7)^(row&7);
      gld16(vpT + (size_t)(h*64+row)*8192 + b*T_ + s0 + j*8,
            &sVT[(it*256+wave*64)*8]);
    }
    __syncthreads();

    if(s0<=qr0+31){
      // ---- S^T = K Q^T, 3-term split ----
      f32x4 sacc[4][2];
#pragma unroll
      for(int st=0;st<4;st++)
#pragma unroll
        for(int mt=0;mt<2;mt++) sacc[st][mt]=zero4();
#pragma unroll
      for(int st=0;st<4;st++)
#pragma unroll
        for(int ksv=0;ksv<2;ksv++){
          const u16* pk=&sK[(st*16+l16)*128];
          const int ch=2*(ksv*4+quad);
          bf16x8 kh=*reinterpret_cast<const bf16x8*>(&pk[((ch  )^sw)*8]);
          bf16x8 kl=*reinterpret_cast<const bf16x8*>(&pk[((ch+1)^sw)*8]);
#pragma unroll
          for(int mt=0;mt<2;mt++){
            sacc[st][mt]=mfma16(kh,qfh[mt][ksv],sacc[st][mt]);
            sacc[st][mt]=mfma16(kl,qfh[mt][ksv],sacc[st][mt]);
            sacc[st][mt]=mfma16(kh,qfl[mt][ksv],sacc[st][mt]);
          }
        }
      const bool needmask=(s0+63>qr0);
      u32 pk_[4][2][2];
      // ---- online softmax over s (x8 folded into exp2; l cross-quad deferred)
#pragma unroll
      for(int mt=0;mt<2;mt++){
        const int qrow=qr0+mt*16+l16;
        float mloc=-1e30f;
#pragma unroll
        for(int st=0;st<4;st++)
#pragma unroll
          for(int r=0;r<4;r++){
            float v=sacc[st][mt][r];
            if(needmask && (s0+st*16+quad*4+r>qrow)) v=-1e30f;
            sacc[st][mt][r]=v;
            mloc=fmaxf(mloc,v);
          }
        mloc=fmaxf(mloc,__shfl_xor(mloc,16,64));
        mloc=fmaxf(mloc,__shfl_xor(mloc,32,64));
        const float nm=fmaxf(mst[mt],mloc);
        const float alpha=exp2f((mst[mt]-nm)*L2E8);
        mst[mt]=nm;
        const float cexp=nm*L2E8;
        float rs=0.f;
#pragma unroll
        for(int st=0;st<4;st++)
#pragma unroll
          for(int r=0;r<4;r++){
            float p=exp2f(__builtin_fmaf(sacc[st][mt][r],L2E8,-cexp));
            sacc[st][mt][r]=p;
            rs+=p;
          }
        lst[mt]=lst[mt]*alpha+rs;        // per-lane partial (this quad's 16 s)
#pragma unroll
        for(int dt=0;dt<4;dt++) oacc[mt][dt]*=alpha;
#pragma unroll
        for(int st=0;st<4;st++){
          pk_[st][mt][0]=pkbf(sacc[st][mt][0],sacc[st][mt][1]);
          pk_[st][mt][1]=pkbf(sacc[st][mt][2],sacc[st][mt][3]);
        }
      }
      // ---- P^T C-layout -> PV B-frag via shfl; O^T += V^T P ----
      const int srcA=(2*(quad&1))*16+l16, srcB=srcA+16;
      const bool hs=(quad>=2);
#pragma unroll
      for(int ksv=0;ksv<2;ksv++){
        bf16x8 b2[2];
#pragma unroll
        for(int mt=0;mt<2;mt++){
          int e0=__shfl((int)pk_[2*ksv  ][mt][0],srcA,64);
          int g0=__shfl((int)pk_[2*ksv+1][mt][0],srcA,64);
          int e1=__shfl((int)pk_[2*ksv  ][mt][1],srcA,64);
          int g1=__shfl((int)pk_[2*ksv+1][mt][1],srcA,64);
          int e2=__shfl((int)pk_[2*ksv  ][mt][0],srcB,64);
          int g2=__shfl((int)pk_[2*ksv+1][mt][0],srcB,64);
          int e3=__shfl((int)pk_[2*ksv  ][mt][1],srcB,64);
          int g3=__shfl((int)pk_[2*ksv+1][mt][1],srcB,64);
          i32x4 bd={ hs?g0:e0, hs?g1:e1, hs?g2:e2, hs?g3:e3 };
          b2[mt]=*reinterpret_cast<bf16x8*>(&bd);
        }
#pragma unroll
        for(int dt=0;dt<4;dt++){
          bf16x8 va=*reinterpret_cast<const bf16x8*>(&sVT[(dt*16+l16)*64 + (((ksv*4+quad)^sw)*8)]);
#pragma unroll
          for(int mt=0;mt<2;mt++)
            oacc[mt][dt]=mfma16(va,b2[mt],oacc[mt][dt]);
        }
      }
    }
  }
  // ---- y = O/l (finish deferred l reduction here) ----
#pragma unroll
  for(int mt=0;mt<2;mt++){
    float lt=lst[mt];
    lt+=__shfl_xor(lt,16,64);
    lt+=__shfl_xor(lt,32,64);
    const float inv=1.0f/lt;
    const size_t rb=(size_t)(b*T_+qr0+mt*16+l16)*1024 + h*64;
#pragma unroll
    for(int dt=0;dt<4;dt++){
      u16x4 o4;
#pragma unroll
      for(int r=0;r<4;r++) o4[r]=f2bf(oacc[mt][dt][r]*inv);
      *reinterpret_cast<u16x4*>(yout + rb + dt*16 + quad*4)=o4;
    }
  }
}

// ---------------------------------------------------------------------------
extern "C" void kernel_launch(void* const* d_in, const int* in_sizes, int n_in,
                              void* d_out, int out_size, void* d_ws, size_t ws_size,
                              hipStream_t stream)
{
  const float* q =(const float*)d_in[0];
  // d_in[1] (k) UNUSED: reference quirk computes kp from qp.
  const float* v =(const float*)d_in[2];
  const float* Wq=(const float*)d_in[3];
  const float* Wk=(const float*)d_in[4];
  const float* Wv=(const float*)d_in[5];
  const float* Wp=(const float*)d_in[6];
  const float* bp=(const float*)d_in[7];
  float* out=(float*)d_out;

  const size_t NE=(size_t)M_*E_;          // 8.39M
  const size_t WE=(size_t)E_*E_;          // 1.05M
  u16* wsv=(u16*)d_ws;
  u16* qsl_i=wsv;                         // [0,2NE): qsplit_i, later kp_i
  u16* qp_i =wsv+2*NE;                    // [2NE,4NE): qp_i, later wp_b
  u16* kp_i =wsv;                         // alias (qsplit dead after G1)
  u16* wp_b =wsv+2*NE;                    // alias (qp dead after attn)
  u16* vpT  =wsv+4*NE;                    // [4NE,5NE)
  u16* ybf  =wsv+5*NE;                    // [5NE,6NE)
  u16* og   =(u16*)d_out;                 // scratch, dead before out-proj
  u16* wq_i =og;                          // 2WE
  u16* wk_i =og+2*WE;                     // 2WE
  u16* wv_b =og+4*WE;                     // WE
  u16* vb   =og+5*WE;                     // NE

  dim3 blk(256);
  cvt_a<<<dim3(NE/2048,2), blk, 0, stream>>>(q, v, qsl_i, vb);
  cvt_w<<<dim3(WE/2048,3), blk, 0, stream>>>(Wq, Wk, Wv, wq_i, wk_i, wv_b);

  dim3 g(E_/128, M_/128);                 // (8, 64)
  // qp = qsplit @ Wq^T  (split)
  gemm<1,0><<<g, blk, 0, stream>>>(qsl_i, wq_i, nullptr, qp_i, nullptr, 0);
  // kp = qp @ Wk^T  (split)
  gemm<1,0><<<g, blk, 0, stream>>>(qp_i, wk_i, nullptr, kp_i, nullptr, 0);
  // vpT[e][b*T+t] = Wv @ v^T  (plain, operand-swapped, ldc=8192)
  gemm<0,1><<<dim3(M_/128, E_/128), blk, 0, stream>>>(wv_b, vb, nullptr, vpT, nullptr, M_);
  // attention -> ybf
  attn<<<dim3(1024), blk, 0, stream>>>(qp_i, kp_i, vpT, ybf);
  // Wp -> bf16 into dead qp region
  cvt_p<<<dim3(WE/2048), blk, 0, stream>>>(Wp, wp_b);
  // out = ybf @ Wp^T + bp
  gemm<0,2><<<g, blk, 0, stream>>>(ybf, wp_b, bp, nullptr, out, E_);
}